// Round 9
// baseline (308.985 us; speedup 1.0000x reference)
//
#include <hip/hip_runtime.h>
#include <math.h>

#define B_ 4
#define T_ 2048
#define D_ 1024
#define H_ 16
#define DK_ 64
#define EPS_ 1e-5f
#define LOG2E 1.44269504f

typedef __attribute__((ext_vector_type(4))) float f32x4;
typedef __attribute__((ext_vector_type(8))) short sv8;
typedef __attribute__((ext_vector_type(4))) short sv4;

__device__ __forceinline__ short f2bf(float f) {
  union { float f; unsigned u; } x; x.f = f;
  unsigned r = x.u + 0x7fffu + ((x.u >> 16) & 1u);
  return (short)(r >> 16);
}

__device__ __forceinline__ void gload16(const void* g, void* l) {
  __builtin_amdgcn_global_load_lds((const __attribute__((address_space(1))) void*)g,
                                   (__attribute__((address_space(3))) void*)l, 16, 0, 0);
}

// ---------------------------------------------------------------------------
// RoPE cos/sin table: cs[t][f] = (cos(t*invf), sin(t*invf))
// ---------------------------------------------------------------------------
__global__ __launch_bounds__(256) void rope_tab(float2* __restrict__ cs) {
  const int i = blockIdx.x * 256 + threadIdx.x;   // < 2048*32
  const int t = i >> 5, f = i & 31;
  const float inv = powf(10000.0f, -(float)f / 32.0f);
  float sn, cn;
  sincosf((float)t * inv, &sn, &cn);
  cs[i] = make_float2(cn, sn);
}

// ---------------------------------------------------------------------------
// LayerNorm: one block per row, float4 per thread. Emits bf16.
// ---------------------------------------------------------------------------
__global__ __launch_bounds__(256) void ln_kernel(const float* __restrict__ x,
                                                 const float* __restrict__ w,
                                                 const float* __restrict__ b,
                                                 short* __restrict__ h) {
  const int row = blockIdx.x;
  const float4 v = ((const float4*)(x + (size_t)row * D_))[threadIdx.x];
  float s  = v.x + v.y + v.z + v.w;
  float ss = v.x*v.x + v.y*v.y + v.z*v.z + v.w*v.w;
  #pragma unroll
  for (int o = 32; o > 0; o >>= 1) {
    s  += __shfl_down(s,  o);
    ss += __shfl_down(ss, o);
  }
  __shared__ float red[8];
  const int wid = threadIdx.x >> 6, lane = threadIdx.x & 63;
  if (lane == 0) { red[wid] = s; red[wid + 4] = ss; }
  __syncthreads();
  s  = red[0] + red[1] + red[2] + red[3];
  ss = red[4] + red[5] + red[6] + red[7];
  const float mu  = s * (1.0f / D_);
  const float var = ss * (1.0f / D_) - mu * mu;
  const float inv = rsqrtf(var + EPS_);
  const float4 wv = ((const float4*)w)[threadIdx.x];
  const float4 bv = ((const float4*)b)[threadIdx.x];
  sv4 o;
  o[0] = f2bf((v.x - mu) * inv * wv.x + bv.x);
  o[1] = f2bf((v.y - mu) * inv * wv.y + bv.y);
  o[2] = f2bf((v.z - mu) * inv * wv.z + bv.z);
  o[3] = f2bf((v.w - mu) * inv * wv.w + bv.w);
  ((sv4*)(h + (size_t)row * D_))[threadIdx.x] = o;
}

// ---------------------------------------------------------------------------
// Transpose + fp32->bf16: WT[n][k] = bf16(W[k][n]).
// ---------------------------------------------------------------------------
__global__ __launch_bounds__(256) void conv_t(const float* __restrict__ W,
                                              short* __restrict__ WT,
                                              int K, int N) {
  __shared__ float tile[32][33];
  const int k0 = blockIdx.y * 32, n0 = blockIdx.x * 32;
  const int tx = threadIdx.x & 31, ty = threadIdx.x >> 5;
  #pragma unroll
  for (int i = 0; i < 4; ++i) {
    const int k = ty * 4 + i;
    tile[k][tx] = W[(size_t)(k0 + k) * N + n0 + tx];
  }
  __syncthreads();
  #pragma unroll
  for (int i = 0; i < 4; ++i) {
    const int n = ty * 4 + i;
    WT[(size_t)(n0 + n) * K + k0 + tx] = f2bf(tile[tx][n]);
  }
}

#define GBM 128
#define GBN 128
#define GBK 32

// stage one 128x32 A-tile + 128x32 B-tile via global_load_lds (LDS-linear)
__device__ __forceinline__ void gstage(const short* __restrict__ A,
                                       const short* __restrict__ BT,
                                       short* AsB, short* BsB,
                                       int tid, size_t aoff, size_t boff) {
  #pragma unroll
  for (int rr = 0; rr < 2; ++rr) {
    const int c = tid + rr * 256;
    const int row = c >> 2, co = (c & 3) * 8;
    gload16(A + aoff + (size_t)row * D_ + co, AsB + c * 8);
    gload16(BT + boff + (size_t)row * D_ + co, BsB + c * 8);
  }
}

// ---------------------------------------------------------------------------
// QKV GEMM + bias + fused RoPE (async dbuf staging, m97 pattern).
// q scaled 0.125*log2e (flash softmax in exp2 domain); v written transposed.
// ---------------------------------------------------------------------------
__global__ __launch_bounds__(256) void gemm_qkv_rope(const short* __restrict__ A,
                                                     const short* __restrict__ BT,
                                                     const float* __restrict__ bias,
                                                     const float2* __restrict__ cs,
                                                     short* __restrict__ qb,
                                                     short* __restrict__ kb,
                                                     short* __restrict__ vt) {
  __shared__ __align__(16) short As[2][GBM][GBK];
  __shared__ __align__(16) short Bs[2][GBN][GBK];
  const int tid = threadIdx.x;
  const int l = tid & 63, g = l >> 4, lq = l & 15;
  const int wm = (tid >> 6) >> 1, wn = (tid >> 6) & 1;
  const int m0 = blockIdx.y * GBM, n0 = blockIdx.x * GBN;

  f32x4 acc[4][4] = {};

  gstage(A, BT, &As[0][0][0], &Bs[0][0][0], tid, (size_t)m0 * D_, (size_t)n0 * D_);
  int cur = 0;
  for (int k0 = 0; k0 < D_; k0 += GBK) {
    __syncthreads();
    if (k0 + GBK < D_)
      gstage(A, BT, &As[cur ^ 1][0][0], &Bs[cur ^ 1][0][0], tid,
             (size_t)m0 * D_ + k0 + GBK, (size_t)n0 * D_ + k0 + GBK);
    sv8 af[4], bf[4];
    #pragma unroll
    for (int mi = 0; mi < 4; ++mi) af[mi] = *(const sv8*)&As[cur][64 * wm + 16 * mi + lq][8 * g];
    #pragma unroll
    for (int ni = 0; ni < 4; ++ni) bf[ni] = *(const sv8*)&Bs[cur][64 * wn + 16 * ni + lq][8 * g];
    #pragma unroll
    for (int mi = 0; mi < 4; ++mi)
      #pragma unroll
      for (int ni = 0; ni < 4; ++ni)
        acc[mi][ni] = __builtin_amdgcn_mfma_f32_16x16x32_bf16(af[mi], bf[ni], acc[mi][ni], 0, 0, 0);
    cur ^= 1;
  }

  const int sec = n0 >> 10;          // uniform per block
  if (sec < 2) {
    short* dst = (sec == 0) ? qb : kb;
    const float qs = (sec == 0) ? 0.125f * LOG2E : 1.0f;
    #pragma unroll
    for (int nA = 0; nA < 2; ++nA) {
      const int colA = n0 + 64 * wn + 16 * nA + lq;
      const float bA = bias[colA], bB = bias[colA + 32];
      const int clA = colA & 1023;
      const int f = 16 * nA + lq;           // 0..31
      #pragma unroll
      for (int mi = 0; mi < 4; ++mi) {
        const int rbase = m0 + 64 * wm + 16 * mi + 4 * g;
        #pragma unroll
        for (int r = 0; r < 4; ++r) {
          const int row = rbase + r, t = row & (T_ - 1);
          const float2 c_s = cs[t * 32 + f];
          const float x1 = acc[mi][nA][r] + bA;
          const float x2 = acc[mi][nA + 2][r] + bB;
          dst[(size_t)row * D_ + clA]      = f2bf((x1 * c_s.x - x2 * c_s.y) * qs);
          dst[(size_t)row * D_ + clA + 32] = f2bf((x2 * c_s.x + x1 * c_s.y) * qs);
        }
      }
    }
  } else {
    #pragma unroll
    for (int ni = 0; ni < 4; ++ni) {
      const int col = n0 + 64 * wn + 16 * ni + lq;
      const float bb = bias[col];
      const int cl = col & 1023;
      const int hh = cl >> 6, d = cl & 63;
      #pragma unroll
      for (int mi = 0; mi < 4; ++mi) {
        const int rbase = m0 + 64 * wm + 16 * mi + 4 * g;
        #pragma unroll
        for (int r = 0; r < 4; ++r) {
          const int row = rbase + r;
          const int bI = row >> 11, t = row & (T_ - 1);
          vt[((size_t)(bI * H_ + hh) * DK_ + d) * T_ + t] = f2bf(acc[mi][ni][r] + bb);
        }
      }
    }
  }
}

// ---------------------------------------------------------------------------
// bf16 MFMA GEMM + bias, fp32 out (out-projection), async dbuf staging.
// ---------------------------------------------------------------------------
__global__ __launch_bounds__(256) void gemm_bf16(const short* __restrict__ A,
                                                 const short* __restrict__ BT,
                                                 const float* __restrict__ bias,
                                                 float* __restrict__ C,
                                                 int M, int N) {
  __shared__ __align__(16) short As[2][GBM][GBK];
  __shared__ __align__(16) short Bs[2][GBN][GBK];
  const int tid = threadIdx.x;
  const int l = tid & 63, g = l >> 4, lq = l & 15;
  const int wm = (tid >> 6) >> 1, wn = (tid >> 6) & 1;
  const int m0 = blockIdx.y * GBM, n0 = blockIdx.x * GBN;

  f32x4 acc[4][4] = {};

  gstage(A, BT, &As[0][0][0], &Bs[0][0][0], tid, (size_t)m0 * D_, (size_t)n0 * D_);
  int cur = 0;
  for (int k0 = 0; k0 < D_; k0 += GBK) {
    __syncthreads();
    if (k0 + GBK < D_)
      gstage(A, BT, &As[cur ^ 1][0][0], &Bs[cur ^ 1][0][0], tid,
             (size_t)m0 * D_ + k0 + GBK, (size_t)n0 * D_ + k0 + GBK);
    sv8 af[4], bf[4];
    #pragma unroll
    for (int mi = 0; mi < 4; ++mi) af[mi] = *(const sv8*)&As[cur][64 * wm + 16 * mi + lq][8 * g];
    #pragma unroll
    for (int ni = 0; ni < 4; ++ni) bf[ni] = *(const sv8*)&Bs[cur][64 * wn + 16 * ni + lq][8 * g];
    #pragma unroll
    for (int mi = 0; mi < 4; ++mi)
      #pragma unroll
      for (int ni = 0; ni < 4; ++ni)
        acc[mi][ni] = __builtin_amdgcn_mfma_f32_16x16x32_bf16(af[mi], bf[ni], acc[mi][ni], 0, 0, 0);
    cur ^= 1;
  }

  #pragma unroll
  for (int ni = 0; ni < 4; ++ni) {
    const int col = n0 + 64 * wn + 16 * ni + lq;
    const float bb = bias[col];
    #pragma unroll
    for (int mi = 0; mi < 4; ++mi) {
      const int rbase = m0 + 64 * wm + 16 * mi + 4 * g;
      #pragma unroll
      for (int r = 0; r < 4; ++r)
        C[(size_t)(rbase + r) * N + col] = acc[mi][ni][r] + bb;
    }
  }
}

// ---------------------------------------------------------------------------
// MFMA flash attention v5: QBLK=128 (each wave owns 32 q rows as two 16-row
// subtiles), R5-proven staging (int4+ds_write, 72-stride, reg prefetch),
// exp2 softmax + defer-max + cvt_pk, skip fully-masked subtiles,
// heavy-blocks-first dispatch, XCD-aware pair mapping (K/V L2-resident).
// ---------------------------------------------------------------------------
__global__ __launch_bounds__(256) void flash_mfma(const short* __restrict__ qb,
                                                  const short* __restrict__ kb,
                                                  const short* __restrict__ vt,
                                                  short* __restrict__ out) {
  __shared__ __align__(16) short Ks[64][72];
  __shared__ __align__(16) short Vt[64][72];
  __shared__ __align__(16) short Ps[4][16][72];

  const int tid = threadIdx.x;
  const int w = tid >> 6, l = tid & 63, g = l >> 4, lq = l & 15;
  const int wg = blockIdx.x;
  const int pair = wg & 63;
  const int bx = (T_ / 128 - 1) - (wg >> 6);    // heavy blocks first
  const int hh = pair & 15, b = pair >> 4;
  const int q0 = bx * 128;
  const int rw = q0 + 32 * w;                   // wave's first q row

  // Q fragments for the two 16-row subtiles (pre-scaled by 0.125*log2e)
  sv8 qf[2][2];
  #pragma unroll
  for (int h = 0; h < 2; ++h) {
    const short* qp = qb + (size_t)(b * T_ + rw + 16 * h + lq) * D_ + hh * DK_;
    qf[h][0] = *(const sv8*)(qp + 8 * g);
    qf[h][1] = *(const sv8*)(qp + 32 + 8 * g);
  }

  f32x4 o[2][4] = {};
  float m_run[2] = {-INFINITY, -INFINITY};
  float l_run[2] = {0.0f, 0.0f};

  const short* kbB = kb + (size_t)(b * T_) * D_ + hh * DK_;
  const short* vtB = vt + (size_t)(b * H_ + hh) * DK_ * T_;
  const int niter = 2 * bx + 2;

  const int skey = tid >> 3, sj = tid & 7;   // staging: key/d row, 8-short chunk

  int4 kr0, kr1, vr0, vr1;
  {
    kr0 = *(const int4*)(kbB + (size_t)(skey)      * D_ + sj * 8);
    kr1 = *(const int4*)(kbB + (size_t)(skey + 32) * D_ + sj * 8);
    vr0 = *(const int4*)(vtB + (size_t)(skey)      * T_ + sj * 8);
    vr1 = *(const int4*)(vtB + (size_t)(skey + 32) * T_ + sj * 8);
  }

  for (int it = 0; it < niter; ++it) {
    const int kv0 = it * 64;
    __syncthreads();
    *(int4*)&Ks[skey][sj * 8]      = kr0;
    *(int4*)&Ks[skey + 32][sj * 8] = kr1;
    *(int4*)&Vt[skey][sj * 8]      = vr0;
    *(int4*)&Vt[skey + 32][sj * 8] = vr1;
    __syncthreads();

    if (it + 1 < niter) {
      const int nk = kv0 + 64;
      kr0 = *(const int4*)(kbB + (size_t)(nk + skey)      * D_ + sj * 8);
      kr1 = *(const int4*)(kbB + (size_t)(nk + skey + 32) * D_ + sj * 8);
      vr0 = *(const int4*)(vtB + (size_t)(skey)      * T_ + nk + sj * 8);
      vr1 = *(const int4*)(vtB + (size_t)(skey + 32) * T_ + nk + sj * 8);
    }

    #pragma unroll
    for (int h = 0; h < 2; ++h) {
      const int rmin = rw + 16 * h;
      if (kv0 > rmin + 15) continue;        // subtile fully masked (wave-uniform)
      const int qrow = rmin + lq;

      // --- QK^T (swapped): lane holds q=lq, keys kt*16+4g+r, exp2 domain ---
      float sv[4][4];
      #pragma unroll
      for (int kt = 0; kt < 4; ++kt) {
        f32x4 acc = {0, 0, 0, 0};
        #pragma unroll
        for (int s = 0; s < 2; ++s) {
          const sv8 kf = *(const sv8*)&Ks[kt * 16 + lq][32 * s + 8 * g];
          acc = __builtin_amdgcn_mfma_f32_16x16x32_bf16(kf, qf[h][s], acc, 0, 0, 0);
        }
        sv[kt][0] = acc[0]; sv[kt][1] = acc[1]; sv[kt][2] = acc[2]; sv[kt][3] = acc[3];
      }

      if (kv0 + 63 > rmin) {                // diagonal tile: causal mask
        #pragma unroll
        for (int kt = 0; kt < 4; ++kt)
          #pragma unroll
          for (int r = 0; r < 4; ++r) {
            const int key_abs = kv0 + kt * 16 + 4 * g + r;
            if (key_abs > qrow) sv[kt][r] = -INFINITY;
          }
      }

      // --- online softmax (exp2 domain, defer-max THR=8) ---
      float tm = -INFINITY;
      #pragma unroll
      for (int kt = 0; kt < 4; ++kt)
        #pragma unroll
        for (int r = 0; r < 4; ++r) tm = fmaxf(tm, sv[kt][r]);
      tm = fmaxf(tm, __shfl_xor(tm, 16));
      tm = fmaxf(tm, __shfl_xor(tm, 32));
      if (__any(tm > m_run[h] + 8.0f)) {
        const float mn = fmaxf(m_run[h], tm);
        const float alpha = __builtin_amdgcn_exp2f(m_run[h] - mn);
        l_run[h] *= alpha;
        #pragma unroll
        for (int r = 0; r < 4; ++r) {
          const float ar = __shfl(alpha, 4 * g + r);
          o[h][0][r] *= ar; o[h][1][r] *= ar; o[h][2][r] *= ar; o[h][3][r] *= ar;
        }
        m_run[h] = mn;
      }
      float psum = 0.0f;
      #pragma unroll
      for (int kt = 0; kt < 4; ++kt)
        #pragma unroll
        for (int r = 0; r < 4; ++r) {
          const float p = __builtin_amdgcn_exp2f(sv[kt][r] - m_run[h]);
          sv[kt][r] = p;
          psum += p;
        }
      psum += __shfl_xor(psum, 16);
      psum += __shfl_xor(psum, 32);
      l_run[h] += psum;

      // --- pack P to bf16 via cvt_pk (per-wave LDS round-trip) ---
      #pragma unroll
      for (int kt = 0; kt < 4; ++kt) {
        unsigned pa_, pb_;
        asm("v_cvt_pk_bf16_f32 %0, %1, %2" : "=v"(pa_) : "v"(sv[kt][0]), "v"(sv[kt][1]));
        asm("v_cvt_pk_bf16_f32 %0, %1, %2" : "=v"(pb_) : "v"(sv[kt][2]), "v"(sv[kt][3]));
        int2 pk; pk.x = (int)pa_; pk.y = (int)pb_;
        *(int2*)&Ps[w][lq][kt * 16 + 4 * g] = pk;
      }

      // --- PV ---
      #pragma unroll
      for (int s = 0; s < 2; ++s) {
        const sv8 pa = *(const sv8*)&Ps[w][lq][32 * s + 8 * g];
        #pragma unroll
        for (int dt = 0; dt < 4; ++dt) {
          const sv8 vb = *(const sv8*)&Vt[dt * 16 + lq][32 * s + 8 * g];
          o[h][dt] = __builtin_amdgcn_mfma_f32_16x16x32_bf16(pa, vb, o[h][dt], 0, 0, 0);
        }
      }
    }
  }

  // --- epilogue ---
  #pragma unroll
  for (int h = 0; h < 2; ++h) {
    #pragma unroll
    for (int r = 0; r < 4; ++r) {
      const float li = __shfl(l_run[h], 4 * g + r);
      const float inv = 1.0f / li;
      const int qr = rw + 16 * h + 4 * g + r;
      short* op = out + (size_t)(b * T_ + qr) * D_ + hh * DK_;
      #pragma unroll
      for (int dt = 0; dt < 4; ++dt)
        op[dt * 16 + lq] = f2bf(o[h][dt][r] * inv);
    }
  }
}

// ---------------------------------------------------------------------------
// launch
// ---------------------------------------------------------------------------
extern "C" void kernel_launch(void* const* d_in, const int* in_sizes, int n_in,
                              void* d_out, int out_size, void* d_ws, size_t ws_size,
                              hipStream_t stream) {
  const float* x     = (const float*)d_in[0];
  const float* ln_w  = (const float*)d_in[1];
  const float* ln_b  = (const float*)d_in[2];
  const float* w_qkv = (const float*)d_in[3];
  const float* b_qkv = (const float*)d_in[4];
  const float* w_o   = (const float*)d_in[5];
  const float* b_o   = (const float*)d_in[6];
  float* outp = (float*)d_out;

  const int rows = B_ * T_;               // 8192
  const size_t nHD = (size_t)rows * D_;   // 8.4M elems

  short* h      = (short*)d_ws;
  short* qb     = h + nHD;
  short* kb     = qb + nHD;
  short* vt     = kb + nHD;
  short* att    = vt + nHD;
  short* wqkvT  = att + nHD;
  short* woT    = wqkvT + (size_t)D_ * 3 * D_;
  float2* csT   = (float2*)(woT + (size_t)D_ * D_);

  rope_tab<<<T_ * 32 / 256, 256, 0, stream>>>(csT);
  conv_t<<<dim3(3 * D_ / 32, D_ / 32), 256, 0, stream>>>(w_qkv, wqkvT, D_, 3 * D_);
  conv_t<<<dim3(D_ / 32, D_ / 32), 256, 0, stream>>>(w_o, woT, D_, D_);

  ln_kernel<<<rows, 256, 0, stream>>>(x, ln_w, ln_b, h);

  {
    dim3 grid(3 * D_ / GBN, rows / GBM);   // (24, 64)
    gemm_qkv_rope<<<grid, 256, 0, stream>>>(h, wqkvT, b_qkv, csT, qb, kb, vt);
  }

  {
    // 1-D grid, XCD-aware: wg -> (pair, bx), 16 q-blocks of 128 rows each
    flash_mfma<<<(T_ / 128) * H_ * B_, 256, 0, stream>>>(qb, kb, vt, att);
  }

  {
    dim3 grid(D_ / GBN, rows / GBM);       // (8, 64)
    gemm_bf16<<<grid, 256, 0, stream>>>(att, woT, b_o, outp, rows, D_);
  }
}